// Round 4
// baseline (209.466 us; speedup 1.0000x reference)
//
#include <hip/hip_runtime.h>
#include <hip/hip_bf16.h>

// GCN layer: h[v] = sum_{e: dst[e]==v} feature[src[e]];  out = h @ W + b
// N=10000 nodes, E=640000 edges, in=128, out=256, all f32.
//
// Strategy: build CSR (by dst) on device each call (ws is re-poisoned), then
// pull-mode aggregation (no float atomics), then f32 vector GEMM.

#define IN_F 128
#define OUT_F 256

// ---------------- CSR build ----------------

__global__ void zero_deg_kernel(int* __restrict__ deg, int n) {
    int i = blockIdx.x * blockDim.x + threadIdx.x;
    if (i < n) deg[i] = 0;
}

__global__ void count_deg_kernel(const int* __restrict__ dst, int* __restrict__ deg, int E) {
    int i = blockIdx.x * blockDim.x + threadIdx.x;
    if (i < E) atomicAdd(&deg[dst[i]], 1);
}

// Single-block exclusive scan over n (<= 1024*PER) elements.
__global__ __launch_bounds__(1024) void scan_kernel(const int* __restrict__ deg,
                                                    int* __restrict__ offs,
                                                    int* __restrict__ cursor, int n) {
    __shared__ int sums[1024];
    const int t = threadIdx.x;
    const int per = (n + 1023) >> 10;  // elements per thread (10 for n=10000)
    int vals[16];
    int base = t * per;
    int local = 0;
    for (int i = 0; i < per; ++i) {
        int idx = base + i;
        int v = (idx < n) ? deg[idx] : 0;
        vals[i] = v;
        local += v;
    }
    sums[t] = local;
    __syncthreads();
    // Hillis-Steele inclusive scan over the 1024 thread sums
    for (int off = 1; off < 1024; off <<= 1) {
        int v = (t >= off) ? sums[t - off] : 0;
        __syncthreads();
        sums[t] += v;
        __syncthreads();
    }
    int running = (t > 0) ? sums[t - 1] : 0;
    for (int i = 0; i < per; ++i) {
        int idx = base + i;
        if (idx < n) { offs[idx] = running; cursor[idx] = running; }
        running += vals[i];
    }
    if (t == 1023) offs[n] = running;
}

__global__ void scatter_kernel(const int* __restrict__ src, const int* __restrict__ dst,
                               int* __restrict__ cursor, int* __restrict__ ssrc, int E) {
    int i = blockIdx.x * blockDim.x + threadIdx.x;
    if (i < E) {
        int p = atomicAdd(&cursor[dst[i]], 1);
        ssrc[p] = src[i];
    }
}

// ---------------- aggregation (pull) ----------------
// One block (128 threads) per destination node; thread t owns feature column t.
__global__ __launch_bounds__(IN_F) void agg_kernel(const float* __restrict__ feat,
                                                   const int* __restrict__ offs,
                                                   const int* __restrict__ ssrc,
                                                   float* __restrict__ h) {
    const int v = blockIdx.x;
    const int t = threadIdx.x;
    const int start = offs[v];
    const int end = offs[v + 1];
    float acc = 0.f;
    int i = start;
    for (; i + 4 <= end; i += 4) {
        int s0 = ssrc[i + 0];
        int s1 = ssrc[i + 1];
        int s2 = ssrc[i + 2];
        int s3 = ssrc[i + 3];
        float f0 = feat[s0 * IN_F + t];
        float f1 = feat[s1 * IN_F + t];
        float f2 = feat[s2 * IN_F + t];
        float f3 = feat[s3 * IN_F + t];
        acc += f0; acc += f1; acc += f2; acc += f3;
    }
    for (; i < end; ++i) acc += feat[ssrc[i] * IN_F + t];
    h[v * IN_F + t] = acc;
}

// ---------------- dense GEMM: out = h @ W + b ----------------
// Block: 256 threads (thread t = output col), 16 rows of h staged in LDS.
#define GROWS 16
__global__ __launch_bounds__(256) void gemm_kernel(const float* __restrict__ h,
                                                   const float* __restrict__ W,
                                                   const float* __restrict__ b,
                                                   float* __restrict__ out) {
    __shared__ float hs[GROWS][IN_F];
    const int t = threadIdx.x;          // 0..255 -> output column
    const int r0 = blockIdx.x * GROWS;  // first row of this block
    // stage 16 h-rows (coalesced)
    for (int i = t; i < GROWS * IN_F; i += 256) {
        int r = i >> 7;       // /128
        int k = i & (IN_F - 1);
        hs[r][k] = h[(r0 + r) * IN_F + k];
    }
    __syncthreads();
    float acc[GROWS];
#pragma unroll
    for (int r = 0; r < GROWS; ++r) acc[r] = 0.f;
#pragma unroll 4
    for (int k = 0; k < IN_F; ++k) {
        float w = W[k * OUT_F + t];  // coalesced, L2-hot (W = 128 KB)
#pragma unroll
        for (int r = 0; r < GROWS; ++r) acc[r] += hs[r][k] * w;  // LDS broadcast
    }
    float bias = b[t];
#pragma unroll
    for (int r = 0; r < GROWS; ++r) out[(r0 + r) * OUT_F + t] = acc[r] + bias;
}

// ---------------- launch ----------------

extern "C" void kernel_launch(void* const* d_in, const int* in_sizes, int n_in,
                              void* d_out, int out_size, void* d_ws, size_t ws_size,
                              hipStream_t stream) {
    const float* feature = (const float*)d_in[0];
    const int* src       = (const int*)d_in[1];
    const int* dst       = (const int*)d_in[2];
    const float* W       = (const float*)d_in[3];
    const float* b       = (const float*)d_in[4];
    float* out = (float*)d_out;

    const int N = in_sizes[0] / IN_F;   // 10000
    const int E = in_sizes[1];          // 640000

    // workspace layout (all re-initialized every call; ws is poisoned 0xAA)
    char* ws = (char*)d_ws;
    int* deg    = (int*)ws;                         // N
    int* offs   = (int*)(ws + 10240 * 4);           // N+1
    int* cursor = (int*)(ws + 2 * 10240 * 4);       // N
    int* ssrc   = (int*)(ws + 3 * 10240 * 4);       // E
    float* h    = (float*)(ws + 3 * 10240 * 4 + (size_t)E * 4);  // N*IN_F

    hipLaunchKernelGGL(zero_deg_kernel, dim3((N + 255) / 256), dim3(256), 0, stream, deg, N);
    hipLaunchKernelGGL(count_deg_kernel, dim3((E + 255) / 256), dim3(256), 0, stream, dst, deg, E);
    hipLaunchKernelGGL(scan_kernel, dim3(1), dim3(1024), 0, stream, deg, offs, cursor, N);
    hipLaunchKernelGGL(scatter_kernel, dim3((E + 255) / 256), dim3(256), 0, stream, src, dst, cursor, ssrc, E);
    hipLaunchKernelGGL(agg_kernel, dim3(N), dim3(IN_F), 0, stream, feature, offs, ssrc, h);
    hipLaunchKernelGGL(gemm_kernel, dim3(N / GROWS), dim3(256), 0, stream, h, W, b, out);
}